// Round 2
// baseline (52589.319 us; speedup 1.0000x reference)
//
#include <hip/hip_runtime.h>
#include <cfloat>

#define NROWS 65536
#define DIM   256
#define KCB   4096

#define BM 128
#define BK 128
#define BD 32
#define LSTR 36   // LDS row stride in floats (36*4B=144B: 16B-aligned, stride-4 banks -> 2-way max, free)

// ---------------- row squared-norms (4 rows per 256-thread block) ----------------
__global__ void norms_kernel(const float* __restrict__ x, float* __restrict__ out) {
  const int row  = blockIdx.x * 4 + (threadIdx.x >> 6);
  const int lane = threadIdx.x & 63;
  const float4 v = ((const float4*)(x + (size_t)row * DIM))[lane];
  float s = v.x * v.x + v.y * v.y + v.z * v.z + v.w * v.w;
  #pragma unroll
  for (int off = 32; off > 0; off >>= 1) s += __shfl_down(s, off);
  if (lane == 0) out[row] = s;
}

// ---------------- fused distance GEMM + argmin ----------------
// dist[n][k] = fp32(fp32(z_norm[n] + e_norm[k]) - 2*dot(z[n], cb[k]))
// argmin with first-index tie-break, replicating numpy fp32 semantics.
// NOTE: accumulation DAG per acc[i][j] must stay identical to the passing
// round-1 kernel (chunks of BD=32, dd steps of 4, dot4 adds in order).
__launch_bounds__(256, 2)
__global__ void argmin_kernel(const float* __restrict__ z,
                              const float* __restrict__ cb,
                              const float* __restrict__ znorm,
                              const float* __restrict__ enorm,
                              int* __restrict__ idx_out) {
  __shared__ float z_s[BM * LSTR];
  __shared__ float e_s[BK * LSTR];
  __shared__ float zn_s[BM];

  const int tid = threadIdx.x;
  const int tx = tid & 15;   // k dimension
  const int ty = tid >> 4;   // row dimension
  const int rbase = blockIdx.x * BM;

  if (tid < BM) zn_s[tid] = znorm[rbase + tid];

  float bestv[8];
  int   besti[8];
  #pragma unroll
  for (int i = 0; i < 8; ++i) { bestv[i] = FLT_MAX; besti[i] = 0; }

  for (int kc = 0; kc < KCB; kc += BK) {
    float acc[8][8];
    #pragma unroll
    for (int i = 0; i < 8; ++i)
      #pragma unroll
      for (int j = 0; j < 8; ++j) acc[i][j] = 0.0f;

    for (int dc = 0; dc < DIM; dc += BD) {
      __syncthreads();
      // stage z-tile [128 x 32] and e-tile [128 x 32] (4 float4 each per thread)
      #pragma unroll
      for (int p = 0; p < 4; ++p) {
        const int el = p * 256 + tid;
        const int r  = el >> 3;
        const int c4 = (el & 7) * 4;
        *(float4*)(&z_s[r * LSTR + c4]) =
            *(const float4*)(z + (size_t)(rbase + r) * DIM + dc + c4);
        *(float4*)(&e_s[r * LSTR + c4]) =
            *(const float4*)(cb + (size_t)(kc + r) * DIM + dc + c4);
      }
      __syncthreads();

      // Register-pressure-aware micro-kernel: keep only b[8] resident,
      // stream a one float4 at a time.  acc(64) + b(32) + a(4) ~= 110 VGPR.
      #pragma unroll
      for (int dd = 0; dd < BD; dd += 4) {
        float4 b[8];
        #pragma unroll
        for (int j = 0; j < 8; ++j)
          b[j] = *(const float4*)(&e_s[(tx + 16 * j) * LSTR + dd]);
        #pragma unroll
        for (int i = 0; i < 8; ++i) {
          const float4 a = *(const float4*)(&z_s[(ty + 16 * i) * LSTR + dd]);
          #pragma unroll
          for (int j = 0; j < 8; ++j)
            acc[i][j] += a.x * b[j].x + a.y * b[j].y +
                         a.z * b[j].z + a.w * b[j].w;
        }
      }
    }

    // per-k-chunk argmin update (ascending k, strict <, lexicographic reduce)
    #pragma unroll
    for (int i = 0; i < 8; ++i) {
      const float zn = zn_s[ty + 16 * i];
      float lv = FLT_MAX; int li = 0;
      #pragma unroll
      for (int j = 0; j < 8; ++j) {
        const int k = kc + tx + 16 * j;
        const float t1 = zn + enorm[k];           // fp32 round (matches np broadcast add)
        const float dist = t1 - 2.0f * acc[i][j]; // fp32 round (2*acc exact)
        if (dist < lv) { lv = dist; li = k; }
      }
      #pragma unroll
      for (int off = 1; off < 16; off <<= 1) {
        const float ov = __shfl_xor(lv, off);
        const int   oi = __shfl_xor(li, off);
        if (ov < lv || (ov == lv && oi < li)) { lv = ov; li = oi; }
      }
      if (lv < bestv[i] || (lv == bestv[i] && li < besti[i])) {
        bestv[i] = lv; besti[i] = li;
      }
    }
  }

  if (tx == 0) {
    #pragma unroll
    for (int i = 0; i < 8; ++i) idx_out[rbase + ty + 16 * i] = besti[i];
  }
}

// ---------------- gather z_q, straight-through output, loss partials ----------------
__global__ void gather_kernel(const float* __restrict__ z,
                              const float* __restrict__ cb,
                              const int* __restrict__ idx,
                              float* __restrict__ out_zq,
                              float* __restrict__ out_idx,
                              float* __restrict__ partials) {
  const int row  = blockIdx.x * 4 + (threadIdx.x >> 6);
  const int lane = threadIdx.x & 63;
  const int k = idx[row];
  const float4 zv = ((const float4*)(z  + (size_t)row * DIM))[lane];
  const float4 ev = ((const float4*)(cb + (size_t)k   * DIM))[lane];
  float4 d, st;
  d.x = ev.x - zv.x; d.y = ev.y - zv.y; d.z = ev.z - zv.z; d.w = ev.w - zv.w;
  st.x = zv.x + d.x; st.y = zv.y + d.y; st.z = zv.z + d.z; st.w = zv.w + d.w;
  ((float4*)(out_zq + (size_t)row * DIM))[lane] = st;
  if (lane == 0) out_idx[row] = (float)k;
  float s = d.x * d.x + d.y * d.y + d.z * d.z + d.w * d.w;
  #pragma unroll
  for (int off = 32; off > 0; off >>= 1) s += __shfl_down(s, off);
  __shared__ float ps[4];
  if (lane == 0) ps[threadIdx.x >> 6] = s;
  __syncthreads();
  if (threadIdx.x == 0)
    partials[blockIdx.x] = (ps[0] + ps[1]) + (ps[2] + ps[3]);
}

// ---------------- loss finalize ----------------
__global__ void loss_kernel(const float* __restrict__ partials,
                            float* __restrict__ out_loss) {
  float s = 0.0f;
  for (int i = threadIdx.x; i < NROWS / 4; i += 256) s += partials[i];
  #pragma unroll
  for (int off = 32; off > 0; off >>= 1) s += __shfl_down(s, off);
  __shared__ float ps[4];
  if ((threadIdx.x & 63) == 0) ps[threadIdx.x >> 6] = s;
  __syncthreads();
  if (threadIdx.x == 0)
    *out_loss = 0.25f * (((ps[0] + ps[1]) + (ps[2] + ps[3])) *
                         (1.0f / (float)((size_t)NROWS * DIM)));
}

extern "C" void kernel_launch(void* const* d_in, const int* in_sizes, int n_in,
                              void* d_out, int out_size, void* d_ws, size_t ws_size,
                              hipStream_t stream) {
  const float* z  = (const float*)d_in[0];   // [65536, 256]
  const float* cb = (const float*)d_in[1];   // [4096, 256]

  float* ws       = (float*)d_ws;
  float* enorm    = ws;                         // 4096
  float* znorm    = ws + KCB;                   // 65536
  int*   idx      = (int*)(ws + KCB + NROWS);   // 65536
  float* partials = ws + KCB + 2 * NROWS;       // 16384

  float* out_zq   = (float*)d_out;
  float* out_idx  = out_zq + (size_t)NROWS * DIM;
  float* out_loss = out_idx + NROWS;

  hipLaunchKernelGGL(norms_kernel, dim3(KCB / 4), dim3(256), 0, stream, cb, enorm);
  hipLaunchKernelGGL(norms_kernel, dim3(NROWS / 4), dim3(256), 0, stream, z, znorm);
  hipLaunchKernelGGL(argmin_kernel, dim3(NROWS / BM), dim3(256), 0, stream,
                     z, cb, znorm, enorm, idx);
  hipLaunchKernelGGL(gather_kernel, dim3(NROWS / 4), dim3(256), 0, stream,
                     z, cb, idx, out_zq, out_idx, partials);
  hipLaunchKernelGGL(loss_kernel, dim3(1), dim3(256), 0, stream, partials, out_loss);
}

// Round 3
// 1988.304 us; speedup vs baseline: 26.4493x; 26.4493x over previous
//
#include <hip/hip_runtime.h>
#include <cfloat>

#define NROWS 65536
#define DIM   256
#define KCB   4096

#define BM 128
#define BK 128
#define BD 32
#define LSTR 36   // LDS row stride in floats (conflict-free per measured SQ_LDS_BANK_CONFLICT=0)

// ---------------- row squared-norms (4 rows per 256-thread block) ----------------
__global__ void norms_kernel(const float* __restrict__ x, float* __restrict__ out) {
  const int row  = blockIdx.x * 4 + (threadIdx.x >> 6);
  const int lane = threadIdx.x & 63;
  const float4 v = ((const float4*)(x + (size_t)row * DIM))[lane];
  float s = v.x * v.x + v.y * v.y + v.z * v.z + v.w * v.w;
  #pragma unroll
  for (int off = 32; off > 0; off >>= 1) s += __shfl_down(s, off);
  if (lane == 0) out[row] = s;
}

// ---------------- fused distance GEMM + argmin ----------------
// dist[n][k] = fp32(fp32(z_norm[n] + e_norm[k]) - 2*dot(z[n], cb[k]))
// argmin with first-index tie-break, replicating numpy fp32 semantics.
// Per-acc accumulation DAG identical to the passing round-1 kernel:
// dc chunks of 32 ascending, dd steps of 4 ascending, fma chain x,y,z,w.
__launch_bounds__(256, 2)
__global__ void argmin_kernel(const float* __restrict__ z,
                              const float* __restrict__ cb,
                              const float* __restrict__ znorm,
                              const float* __restrict__ enorm,
                              int* __restrict__ idx_out) {
  __shared__ float z_s[BM * LSTR];
  __shared__ float e_s[BK * LSTR];
  __shared__ float zn_s[BM];

  const int tid = threadIdx.x;
  const int tx = tid & 15;   // k dimension
  const int ty = tid >> 4;   // row dimension
  const int rbase = blockIdx.x * BM;

  if (tid < BM) zn_s[tid] = znorm[rbase + tid];

  // per-thread running argmin over this thread's k subset {kc + tx + 16j}
  float bestv[8];
  int   besti[8];
  #pragma unroll
  for (int i = 0; i < 8; ++i) { bestv[i] = FLT_MAX; besti[i] = 0; }

  for (int kc = 0; kc < KCB; kc += BK) {
    float acc[8][8];
    #pragma unroll
    for (int i = 0; i < 8; ++i)
      #pragma unroll
      for (int j = 0; j < 8; ++j) acc[i][j] = 0.0f;

    for (int dc = 0; dc < DIM; dc += BD) {
      __syncthreads();
      // stage z-tile [128 x 32] and e-tile [128 x 32] (4 float4 each per thread)
      #pragma unroll
      for (int p = 0; p < 4; ++p) {
        const int el = p * 256 + tid;
        const int r  = el >> 3;
        const int c4 = (el & 7) * 4;
        *(float4*)(&z_s[r * LSTR + c4]) =
            *(const float4*)(z + (size_t)(rbase + r) * DIM + dc + c4);
        *(float4*)(&e_s[r * LSTR + c4]) =
            *(const float4*)(cb + (size_t)(kc + r) * DIM + dc + c4);
      }
      __syncthreads();

      // unroll 1: block cross-iteration ds_read hoisting -> live set stays
      // acc(64)+b(32)+a(4)+addr ~= 115 VGPR, no spill.
      #pragma unroll 1
      for (int dd = 0; dd < BD; dd += 4) {
        float4 b[8];
        #pragma unroll
        for (int j = 0; j < 8; ++j)
          b[j] = *(const float4*)(&e_s[(tx + 16 * j) * LSTR + dd]);
        #pragma unroll
        for (int i = 0; i < 8; ++i) {
          const float4 a = *(const float4*)(&z_s[(ty + 16 * i) * LSTR + dd]);
          #pragma unroll
          for (int j = 0; j < 8; ++j)
            acc[i][j] += a.x * b[j].x + a.y * b[j].y +
                         a.z * b[j].z + a.w * b[j].w;
        }
      }
    }

    // per-kc argmin update; cross-lane reduce deferred to kernel end.
    float en[8];
    #pragma unroll
    for (int j = 0; j < 8; ++j) en[j] = enorm[kc + tx + 16 * j];

    #pragma unroll
    for (int i = 0; i < 8; ++i) {
      const float zn = zn_s[ty + 16 * i];
      #pragma unroll
      for (int j = 0; j < 8; ++j) {
        const float t1 = zn + en[j];              // fp32 round (matches np broadcast add)
        const float dist = t1 - 2.0f * acc[i][j]; // fp32 round (2*acc exact)
        const int k = kc + tx + 16 * j;           // ascending within thread
        if (dist < bestv[i]) { bestv[i] = dist; besti[i] = k; }
      }
    }
  }

  // final cross-lane (16 tx lanes) lexicographic min reduce, once
  #pragma unroll
  for (int i = 0; i < 8; ++i) {
    float lv = bestv[i]; int li = besti[i];
    #pragma unroll
    for (int off = 1; off < 16; off <<= 1) {
      const float ov = __shfl_xor(lv, off);
      const int   oi = __shfl_xor(li, off);
      if (ov < lv || (ov == lv && oi < li)) { lv = ov; li = oi; }
    }
    if (tx == 0) idx_out[rbase + ty + 16 * i] = li;
  }
}

// ---------------- gather z_q, straight-through output, loss partials ----------------
__global__ void gather_kernel(const float* __restrict__ z,
                              const float* __restrict__ cb,
                              const int* __restrict__ idx,
                              float* __restrict__ out_zq,
                              float* __restrict__ out_idx,
                              float* __restrict__ partials) {
  const int row  = blockIdx.x * 4 + (threadIdx.x >> 6);
  const int lane = threadIdx.x & 63;
  const int k = idx[row];
  const float4 zv = ((const float4*)(z  + (size_t)row * DIM))[lane];
  const float4 ev = ((const float4*)(cb + (size_t)k   * DIM))[lane];
  float4 d, st;
  d.x = ev.x - zv.x; d.y = ev.y - zv.y; d.z = ev.z - zv.z; d.w = ev.w - zv.w;
  st.x = zv.x + d.x; st.y = zv.y + d.y; st.z = zv.z + d.z; st.w = zv.w + d.w;
  ((float4*)(out_zq + (size_t)row * DIM))[lane] = st;
  if (lane == 0) out_idx[row] = (float)k;
  float s = d.x * d.x + d.y * d.y + d.z * d.z + d.w * d.w;
  #pragma unroll
  for (int off = 32; off > 0; off >>= 1) s += __shfl_down(s, off);
  __shared__ float ps[4];
  if (lane == 0) ps[threadIdx.x >> 6] = s;
  __syncthreads();
  if (threadIdx.x == 0)
    partials[blockIdx.x] = (ps[0] + ps[1]) + (ps[2] + ps[3]);
}

// ---------------- loss finalize ----------------
__global__ void loss_kernel(const float* __restrict__ partials,
                            float* __restrict__ out_loss) {
  float s = 0.0f;
  for (int i = threadIdx.x; i < NROWS / 4; i += 256) s += partials[i];
  #pragma unroll
  for (int off = 32; off > 0; off >>= 1) s += __shfl_down(s, off);
  __shared__ float ps[4];
  if ((threadIdx.x & 63) == 0) ps[threadIdx.x >> 6] = s;
  __syncthreads();
  if (threadIdx.x == 0)
    *out_loss = 0.25f * (((ps[0] + ps[1]) + (ps[2] + ps[3])) *
                         (1.0f / (float)((size_t)NROWS * DIM)));
}

extern "C" void kernel_launch(void* const* d_in, const int* in_sizes, int n_in,
                              void* d_out, int out_size, void* d_ws, size_t ws_size,
                              hipStream_t stream) {
  const float* z  = (const float*)d_in[0];   // [65536, 256]
  const float* cb = (const float*)d_in[1];   // [4096, 256]

  float* ws       = (float*)d_ws;
  float* enorm    = ws;                         // 4096
  float* znorm    = ws + KCB;                   // 65536
  int*   idx      = (int*)(ws + KCB + NROWS);   // 65536
  float* partials = ws + KCB + 2 * NROWS;       // 16384

  float* out_zq   = (float*)d_out;
  float* out_idx  = out_zq + (size_t)NROWS * DIM;
  float* out_loss = out_idx + NROWS;

  hipLaunchKernelGGL(norms_kernel, dim3(KCB / 4), dim3(256), 0, stream, cb, enorm);
  hipLaunchKernelGGL(norms_kernel, dim3(NROWS / 4), dim3(256), 0, stream, z, znorm);
  hipLaunchKernelGGL(argmin_kernel, dim3(NROWS / BM), dim3(256), 0, stream,
                     z, cb, znorm, enorm, idx);
  hipLaunchKernelGGL(gather_kernel, dim3(NROWS / 4), dim3(256), 0, stream,
                     z, cb, idx, out_zq, out_idx, partials);
  hipLaunchKernelGGL(loss_kernel, dim3(1), dim3(256), 0, stream, partials, out_loss);
}

// Round 4
// 474.266 us; speedup vs baseline: 110.8858x; 4.1924x over previous
//
#include <hip/hip_runtime.h>
#include <cfloat>

#define NROWS 65536
#define DIM   256
#define KCB   4096

#define EPS_WIN  1.8e-4f
#define CAND_CAP 16

typedef __attribute__((ext_vector_type(8))) short short8;
typedef __attribute__((ext_vector_type(4))) float f32x4;

// ---------------- row squared-norms (4 rows per 256-thread block) ----------------
__global__ void norms_kernel(const float* __restrict__ x, float* __restrict__ out) {
  const int row  = blockIdx.x * 4 + (threadIdx.x >> 6);
  const int lane = threadIdx.x & 63;
  const float4 v = ((const float4*)(x + (size_t)row * DIM))[lane];
  float s = v.x * v.x + v.y * v.y + v.z * v.z + v.w * v.w;
  #pragma unroll
  for (int off = 32; off > 0; off >>= 1) s += __shfl_down(s, off);
  if (lane == 0) out[row] = s;
}

// ---------------- fp32 -> bf16 RNE ----------------
__device__ inline unsigned short f2bf(float x) {
  unsigned int u = __float_as_uint(x);
  return (unsigned short)((u + 0x7fffu + ((u >> 16) & 1u)) >> 16);
}

__global__ void prep_kernel(const float* __restrict__ z, const float* __restrict__ cb,
                            unsigned short* __restrict__ zh, unsigned short* __restrict__ eh) {
  const long long j = (long long)blockIdx.x * 256 + threadIdx.x;
  const long long NZ8 = (long long)NROWS * DIM / 8;
  const float* src; unsigned short* dst; long long base;
  if (j < NZ8) { src = z;  dst = zh; base = j * 8; }
  else         { src = cb; dst = eh; base = (j - NZ8) * 8; }
  const float4 v0 = *(const float4*)(src + base);
  const float4 v1 = *(const float4*)(src + base + 4);
  union { unsigned short us[8]; uint4 u4; } o;
  o.us[0] = f2bf(v0.x); o.us[1] = f2bf(v0.y); o.us[2] = f2bf(v0.z); o.us[3] = f2bf(v0.w);
  o.us[4] = f2bf(v1.x); o.us[5] = f2bf(v1.y); o.us[6] = f2bf(v1.z); o.us[7] = f2bf(v1.w);
  *(uint4*)(dst + base) = o.u4;
}

// ---------------- MFMA screen: per-row min + candidate window ----------------
// Block: 128 rows x 128 codes per kc-tile, 4 waves, wave owns 32 rows x 128 cols
// (2 frag-rows x 8 frag-cols of 16x16x32 bf16 MFMA). A (zh rows) resident in
// swizzled LDS full-depth; B chunks staged per (kc,dc), XOR-swizzled (2-way free).
__launch_bounds__(256, 2)
__global__ void screen_kernel(const unsigned short* __restrict__ zh,
                              const unsigned short* __restrict__ eh,
                              const float* __restrict__ znorm,
                              const float* __restrict__ enorm,
                              unsigned int* __restrict__ counts,
                              unsigned short* __restrict__ cands) {
  __shared__ __align__(16) unsigned short a_s[128 * 256];   // 64KB, row=512B, slot=16B ^ (row&7)
  __shared__ __align__(16) unsigned short b_s[128 * 32];    // 8KB,  row=64B,  slot=16B ^ ((c>>1)&3)
  __shared__ float zn_s[128];
  __shared__ unsigned int cnt_s[128];
  __shared__ unsigned short cand_s[128 * CAND_CAP];

  const int tid = threadIdx.x;
  const int wv  = tid >> 6;
  const int ln  = tid & 63;
  const int l15 = ln & 15;
  const int lg  = ln >> 4;
  const int rbase = blockIdx.x * 128;

  if (tid < 128) { zn_s[tid] = znorm[rbase + tid]; cnt_s[tid] = 0u; }

  // stage A once (swizzled): granule gid = i*256+tid -> row=gid>>5, slot=gid&31
  #pragma unroll 1
  for (int i = 0; i < 16; ++i) {
    const int gid = i * 256 + tid;
    const int row = gid >> 5, slot = gid & 31;
    const int sw  = slot ^ (row & 7);
    *(uint4*)(&a_s[row * 256 + sw * 8]) =
        *(const uint4*)(&zh[(size_t)(rbase + row) * 256 + slot * 8]);
  }
  __syncthreads();

  // per-thread row-slot ids: row = wv*32 + fr*16 + lg*4 + q
  float znv[8];
  #pragma unroll
  for (int fr = 0; fr < 2; ++fr)
    #pragma unroll
    for (int q = 0; q < 4; ++q)
      znv[fr * 4 + q] = zn_s[wv * 32 + fr * 16 + lg * 4 + q];

  float rm[8];
  #pragma unroll
  for (int s = 0; s < 8; ++s) rm[s] = FLT_MAX;

  #pragma unroll 1
  for (int kt = 0; kt < KCB / 128; ++kt) {
    const int kcb0 = kt * 128;
    f32x4 acc[2][8];
    #pragma unroll
    for (int fr = 0; fr < 2; ++fr)
      #pragma unroll
      for (int fc = 0; fc < 8; ++fc)
        acc[fr][fc] = (f32x4){0.f, 0.f, 0.f, 0.f};

    #pragma unroll 1
    for (int dc = 0; dc < 8; ++dc) {
      __syncthreads();   // protect b_s from previous iteration's readers
      // stage B chunk [128 codes x 32 depth]: c = i*64 + wv*16 + l15, slot = lg
      #pragma unroll
      for (int i = 0; i < 2; ++i) {
        const int c  = i * 64 + wv * 16 + l15;
        const int sw = lg ^ ((c >> 1) & 3);
        *(uint4*)(&b_s[c * 32 + sw * 8]) =
            *(const uint4*)(&eh[(size_t)(kcb0 + c) * 256 + dc * 32 + lg * 8]);
      }
      __syncthreads();

      short8 af[2];
      #pragma unroll
      for (int fr = 0; fr < 2; ++fr) {
        const int r = wv * 32 + fr * 16 + l15;
        const int sl = (dc * 4 + lg) ^ (r & 7);
        af[fr] = *(const short8*)(&a_s[r * 256 + sl * 8]);
      }
      short8 bf[8];
      #pragma unroll
      for (int fc = 0; fc < 8; ++fc) {
        const int c = fc * 16 + l15;
        const int sw = lg ^ ((c >> 1) & 3);
        bf[fc] = *(const short8*)(&b_s[c * 32 + sw * 8]);
      }
      #pragma unroll
      for (int fr = 0; fr < 2; ++fr)
        #pragma unroll
        for (int fc = 0; fc < 8; ++fc)
          acc[fr][fc] = __builtin_amdgcn_mfma_f32_16x16x32_bf16(
              af[fr], bf[fc], acc[fr][fc], 0, 0, 0);
    }

    // ---- epilogue: dist, tile-min, window append, runmin update ----
    float en_[8];
    #pragma unroll
    for (int fc = 0; fc < 8; ++fc) en_[fc] = enorm[kcb0 + fc * 16 + l15];

    float tm[8];
    #pragma unroll
    for (int s = 0; s < 8; ++s) tm[s] = FLT_MAX;

    #pragma unroll
    for (int fr = 0; fr < 2; ++fr)
      #pragma unroll
      for (int fc = 0; fc < 8; ++fc)
        #pragma unroll
        for (int q = 0; q < 4; ++q) {
          const float d_ = fmaf(-2.0f, acc[fr][fc][q], znv[fr * 4 + q] + en_[fc]);
          tm[fr * 4 + q] = fminf(tm[fr * 4 + q], d_);
        }

    float th[8];
    #pragma unroll
    for (int s = 0; s < 8; ++s) {
      float v = tm[s];
      v = fminf(v, __shfl_xor(v, 1));
      v = fminf(v, __shfl_xor(v, 2));
      v = fminf(v, __shfl_xor(v, 4));
      v = fminf(v, __shfl_xor(v, 8));
      const float m = fminf(rm[s], v);
      rm[s] = m;
      th[s] = m + EPS_WIN;
    }

    #pragma unroll
    for (int fr = 0; fr < 2; ++fr)
      #pragma unroll
      for (int fc = 0; fc < 8; ++fc)
        #pragma unroll
        for (int q = 0; q < 4; ++q) {
          const float d_ = fmaf(-2.0f, acc[fr][fc][q], znv[fr * 4 + q] + en_[fc]);
          if (d_ <= th[fr * 4 + q]) {
            const int rl = wv * 32 + fr * 16 + lg * 4 + q;
            const unsigned int pos = atomicAdd(&cnt_s[rl], 1u);
            if (pos < CAND_CAP)
              cand_s[rl * CAND_CAP + pos] = (unsigned short)(kcb0 + fc * 16 + l15);
          }
        }
  }

  __syncthreads();
  if (tid < 128) counts[rbase + tid] = cnt_s[tid];
  for (int i = tid; i < 128 * CAND_CAP; i += 256)
    cands[(size_t)rbase * CAND_CAP + i] = cand_s[i];
}

// ---------------- exact fp32 rescore of candidates (serial fma chain) ----------------
__global__ void rescore_kernel(const float* __restrict__ z, const float* __restrict__ cb,
                               const float* __restrict__ znorm, const float* __restrict__ enorm,
                               const unsigned int* __restrict__ counts,
                               const unsigned short* __restrict__ cands,
                               int* __restrict__ idx) {
  const int gw  = (blockIdx.x * 256 + threadIdx.x) >> 6;   // global wave id
  const int ln  = threadIdx.x & 63;
  const int row = gw * 4 + (ln >> 4);
  const int ci  = ln & 15;
  const unsigned int cnt = counts[row];

  float bv = FLT_MAX; int bk = 0x7fffffff;
  if (cnt <= CAND_CAP) {
    const int active = ci < (int)cnt;
    const int k = active ? (int)cands[(size_t)row * CAND_CAP + ci] : 0;
    const float* zr = z  + (size_t)row * DIM;
    const float* er = cb + (size_t)k   * DIM;
    float acc = 0.0f;
    #pragma unroll 8
    for (int d = 0; d < DIM; ++d) acc = fmaf(zr[d], er[d], acc);
    const float dist = fmaf(-2.0f, acc, znorm[row] + enorm[k]);
    if (active) { bv = dist; bk = k; }
  }
  #pragma unroll
  for (int off = 1; off < 16; off <<= 1) {
    const float ov = __shfl_xor(bv, off);
    const int   ok = __shfl_xor(bk, off);
    if (ov < bv || (ov == bv && ok < bk)) { bv = ov; bk = ok; }
  }
  if (ci == 0 && cnt <= CAND_CAP) idx[row] = bk;
}

// ---------------- fallback: exact full rescan for cap-overflow rows ----------------
__global__ void fallback_kernel(const float* __restrict__ z, const float* __restrict__ cb,
                                const float* __restrict__ znorm, const float* __restrict__ enorm,
                                const unsigned int* __restrict__ counts,
                                int* __restrict__ idx) {
  __shared__ float bd_s[256];
  __shared__ int   bk_s[256];
  const int tid = threadIdx.x;
  for (int row = blockIdx.x; row < NROWS; row += gridDim.x) {
    if (counts[row] <= CAND_CAP) continue;   // uniform per block
    const float zn = znorm[row];
    const float* zr = z + (size_t)row * DIM;
    float bv = FLT_MAX; int bk = 0x7fffffff;
    for (int k = tid; k < KCB; k += 256) {
      const float* er = cb + (size_t)k * DIM;
      float acc = 0.0f;
      #pragma unroll 8
      for (int d = 0; d < DIM; ++d) acc = fmaf(zr[d], er[d], acc);
      const float dist = fmaf(-2.0f, acc, zn + enorm[k]);
      if (dist < bv || (dist == bv && k < bk)) { bv = dist; bk = k; }
    }
    bd_s[tid] = bv; bk_s[tid] = bk;
    __syncthreads();
    for (int s = 128; s > 0; s >>= 1) {
      if (tid < s) {
        const float ov = bd_s[tid + s]; const int ok = bk_s[tid + s];
        if (ov < bd_s[tid] || (ov == bd_s[tid] && ok < bk_s[tid])) {
          bd_s[tid] = ov; bk_s[tid] = ok;
        }
      }
      __syncthreads();
    }
    if (tid == 0) idx[row] = bk_s[0];
    __syncthreads();
  }
}

// ---------------- legacy fp32 argmin (round-3, used if ws too small) ----------------
#define BM 128
#define BK 128
#define BD 32
#define LSTR 36
__launch_bounds__(256, 2)
__global__ void argmin_kernel(const float* __restrict__ z,
                              const float* __restrict__ cb,
                              const float* __restrict__ znorm,
                              const float* __restrict__ enorm,
                              int* __restrict__ idx_out) {
  __shared__ float z_s[BM * LSTR];
  __shared__ float e_s[BK * LSTR];
  __shared__ float zn_s[BM];
  const int tid = threadIdx.x;
  const int tx = tid & 15;
  const int ty = tid >> 4;
  const int rbase = blockIdx.x * BM;
  if (tid < BM) zn_s[tid] = znorm[rbase + tid];
  float bestv[8]; int besti[8];
  #pragma unroll
  for (int i = 0; i < 8; ++i) { bestv[i] = FLT_MAX; besti[i] = 0; }
  for (int kc = 0; kc < KCB; kc += BK) {
    float acc[8][8];
    #pragma unroll
    for (int i = 0; i < 8; ++i)
      #pragma unroll
      for (int j = 0; j < 8; ++j) acc[i][j] = 0.0f;
    for (int dc = 0; dc < DIM; dc += BD) {
      __syncthreads();
      #pragma unroll
      for (int p = 0; p < 4; ++p) {
        const int el = p * 256 + tid;
        const int r  = el >> 3;
        const int c4 = (el & 7) * 4;
        *(float4*)(&z_s[r * LSTR + c4]) =
            *(const float4*)(z + (size_t)(rbase + r) * DIM + dc + c4);
        *(float4*)(&e_s[r * LSTR + c4]) =
            *(const float4*)(cb + (size_t)(kc + r) * DIM + dc + c4);
      }
      __syncthreads();
      #pragma unroll 1
      for (int dd = 0; dd < BD; dd += 4) {
        float4 b[8];
        #pragma unroll
        for (int j = 0; j < 8; ++j)
          b[j] = *(const float4*)(&e_s[(tx + 16 * j) * LSTR + dd]);
        #pragma unroll
        for (int i = 0; i < 8; ++i) {
          const float4 a = *(const float4*)(&z_s[(ty + 16 * i) * LSTR + dd]);
          #pragma unroll
          for (int j = 0; j < 8; ++j)
            acc[i][j] += a.x * b[j].x + a.y * b[j].y + a.z * b[j].z + a.w * b[j].w;
        }
      }
    }
    float en[8];
    #pragma unroll
    for (int j = 0; j < 8; ++j) en[j] = enorm[kc + tx + 16 * j];
    #pragma unroll
    for (int i = 0; i < 8; ++i) {
      const float zn = zn_s[ty + 16 * i];
      #pragma unroll
      for (int j = 0; j < 8; ++j) {
        const float t1 = zn + en[j];
        const float dist = t1 - 2.0f * acc[i][j];
        const int k = kc + tx + 16 * j;
        if (dist < bestv[i]) { bestv[i] = dist; besti[i] = k; }
      }
    }
  }
  #pragma unroll
  for (int i = 0; i < 8; ++i) {
    float lv = bestv[i]; int li = besti[i];
    #pragma unroll
    for (int off = 1; off < 16; off <<= 1) {
      const float ov = __shfl_xor(lv, off);
      const int   oi = __shfl_xor(li, off);
      if (ov < lv || (ov == lv && oi < li)) { lv = ov; li = oi; }
    }
    if (tx == 0) idx_out[rbase + ty + 16 * i] = li;
  }
}

// ---------------- gather z_q, straight-through output, loss partials ----------------
__global__ void gather_kernel(const float* __restrict__ z,
                              const float* __restrict__ cb,
                              const int* __restrict__ idx,
                              float* __restrict__ out_zq,
                              float* __restrict__ out_idx,
                              float* __restrict__ partials) {
  const int row  = blockIdx.x * 4 + (threadIdx.x >> 6);
  const int lane = threadIdx.x & 63;
  const int k = idx[row];
  const float4 zv = ((const float4*)(z  + (size_t)row * DIM))[lane];
  const float4 ev = ((const float4*)(cb + (size_t)k   * DIM))[lane];
  float4 d, st;
  d.x = ev.x - zv.x; d.y = ev.y - zv.y; d.z = ev.z - zv.z; d.w = ev.w - zv.w;
  st.x = zv.x + d.x; st.y = zv.y + d.y; st.z = zv.z + d.z; st.w = zv.w + d.w;
  ((float4*)(out_zq + (size_t)row * DIM))[lane] = st;
  if (lane == 0) out_idx[row] = (float)k;
  float s = d.x * d.x + d.y * d.y + d.z * d.z + d.w * d.w;
  #pragma unroll
  for (int off = 32; off > 0; off >>= 1) s += __shfl_down(s, off);
  __shared__ float ps[4];
  if (lane == 0) ps[threadIdx.x >> 6] = s;
  __syncthreads();
  if (threadIdx.x == 0)
    partials[blockIdx.x] = (ps[0] + ps[1]) + (ps[2] + ps[3]);
}

__global__ void loss_kernel(const float* __restrict__ partials,
                            float* __restrict__ out_loss) {
  float s = 0.0f;
  for (int i = threadIdx.x; i < NROWS / 4; i += 256) s += partials[i];
  #pragma unroll
  for (int off = 32; off > 0; off >>= 1) s += __shfl_down(s, off);
  __shared__ float ps[4];
  if ((threadIdx.x & 63) == 0) ps[threadIdx.x >> 6] = s;
  __syncthreads();
  if (threadIdx.x == 0)
    *out_loss = 0.25f * (((ps[0] + ps[1]) + (ps[2] + ps[3])) *
                         (1.0f / (float)((size_t)NROWS * DIM)));
}

extern "C" void kernel_launch(void* const* d_in, const int* in_sizes, int n_in,
                              void* d_out, int out_size, void* d_ws, size_t ws_size,
                              hipStream_t stream) {
  const float* z  = (const float*)d_in[0];   // [65536, 256]
  const float* cb = (const float*)d_in[1];   // [4096, 256]

  float* out_zq   = (float*)d_out;
  float* out_idx  = out_zq + (size_t)NROWS * DIM;
  float* out_loss = out_idx + NROWS;

  // fast-path workspace layout (bytes)
  char* w = (char*)d_ws;
  unsigned short* zh    = (unsigned short*)(w);                   // 33554432
  unsigned short* eh    = (unsigned short*)(w + 33554432);        //  2097152
  float* enorm          = (float*)(w + 35651584);                 //    16384
  float* znorm          = (float*)(w + 35667968);                 //   262144
  int*   idx            = (int*)(w + 35930112);                   //   262144
  unsigned int* counts  = (unsigned int*)(w + 36192256);          //   262144
  unsigned short* cands = (unsigned short*)(w + 36454400);        //  2097152
  float* partials       = (float*)(w + 38551552);                 //    65536
  const size_t NEED = 38617088;

  if (ws_size >= NEED) {
    hipLaunchKernelGGL(norms_kernel, dim3(KCB / 4), dim3(256), 0, stream, cb, enorm);
    hipLaunchKernelGGL(norms_kernel, dim3(NROWS / 4), dim3(256), 0, stream, z, znorm);
    hipLaunchKernelGGL(prep_kernel, dim3((NROWS * DIM / 8 + KCB * DIM / 8) / 256),
                       dim3(256), 0, stream, z, cb, zh, eh);
    hipLaunchKernelGGL(screen_kernel, dim3(NROWS / 128), dim3(256), 0, stream,
                       zh, eh, znorm, enorm, counts, cands);
    hipLaunchKernelGGL(rescore_kernel, dim3(NROWS / 16), dim3(256), 0, stream,
                       z, cb, znorm, enorm, counts, cands, idx);
    hipLaunchKernelGGL(fallback_kernel, dim3(256), dim3(256), 0, stream,
                       z, cb, znorm, enorm, counts, idx);
    hipLaunchKernelGGL(gather_kernel, dim3(NROWS / 4), dim3(256), 0, stream,
                       z, cb, idx, out_zq, out_idx, partials);
    hipLaunchKernelGGL(loss_kernel, dim3(1), dim3(256), 0, stream, partials, out_loss);
  } else {
    // legacy (round-3) layout + path
    float* ws        = (float*)d_ws;
    float* enorm_l   = ws;
    float* znorm_l   = ws + KCB;
    int*   idx_l     = (int*)(ws + KCB + NROWS);
    float* partials_l= ws + KCB + 2 * NROWS;
    hipLaunchKernelGGL(norms_kernel, dim3(KCB / 4), dim3(256), 0, stream, cb, enorm_l);
    hipLaunchKernelGGL(norms_kernel, dim3(NROWS / 4), dim3(256), 0, stream, z, znorm_l);
    hipLaunchKernelGGL(argmin_kernel, dim3(NROWS / BM), dim3(256), 0, stream,
                       z, cb, znorm_l, enorm_l, idx_l);
    hipLaunchKernelGGL(gather_kernel, dim3(NROWS / 4), dim3(256), 0, stream,
                       z, cb, idx_l, out_zq, out_idx, partials_l);
    hipLaunchKernelGGL(loss_kernel, dim3(1), dim3(256), 0, stream, partials_l, out_loss);
  }
}